// Round 5
// baseline (1060.768 us; speedup 1.0000x reference)
//
#include <hip/hip_runtime.h>
#include <math.h>

#define N_NODES 50000
#define E_EDGES 800000
#define EP_EDGES 200000
#define NG4 (4 * N_NODES)
#define ETOT (4 * E_EDGES)
#define NBUCK 196   // ceil(50000/256)

static inline int idiv(int a, int b) { return (a + b - 1) / b; }

typedef short s16x8 __attribute__((ext_vector_type(8)));
typedef float f32x4 __attribute__((ext_vector_type(4)));
typedef unsigned short us;

static __device__ __forceinline__ us f2bf(float f) {
  unsigned int u = __float_as_uint(f);
  u += 0x7FFFu + ((u >> 16) & 1u);
  return (us)(u >> 16);
}
static __device__ __forceinline__ float bflo(unsigned int u) { return __uint_as_float(u << 16); }
static __device__ __forceinline__ float bfhi(unsigned int u) { return __uint_as_float(u & 0xffff0000u); }

// ---------------- weight transpose+convert (only the 3 still-needed mats) ----------------
__global__ __launch_bounds__(256) void wtrans3_k(
    const float* __restrict__ prW1, const float* __restrict__ pW1,
    const float* __restrict__ gaW1,
    us* __restrict__ prW1t, us* __restrict__ WaPt, us* __restrict__ WaGt)
{
  const float* src; us* dst; int ks, nsh, total;
  switch (blockIdx.z) {
    case 0: src = prW1; dst = prW1t; ks = 8; nsh = 7; total = 32768; break;
    case 1: src = pW1;  dst = WaPt;  ks = 7; nsh = 7; total = 16384; break;
    default: src = gaW1; dst = WaGt; ks = 7; nsh = 7; total = 16384; break;
  }
  int Km1 = (1 << ks) - 1;
  for (int gid = blockIdx.x * 256 + threadIdx.x; gid < total; gid += gridDim.x * 256) {
    int n = gid >> ks, k = gid & Km1;
    dst[gid] = f2bf(src[((size_t)k << nsh) + n]);
  }
}

// ---------------- combined weights: Wc[k][n] = sum_m Wp[k][m] * Wg[m][n], stored [zi*128+n][k] bf16 ----
// side 0: Wp=W2 (K=1024), zi -> z {0,1,3,6} -> Wg {Ws0, Wd0, Wd1, Ws3}
// side 1: Wp=W1 (K=512),  zi -> z {2,4,5,7} -> Wg {Ws1, Ws2, Wd2, Wd3}
__global__ __launch_bounds__(128) void wcomb_k(
    const float* __restrict__ W2, const float* __restrict__ W1,
    const float* __restrict__ gWs, const float* __restrict__ gWd,
    us* __restrict__ WcPE, us* __restrict__ WcGE)
{
  const int side = blockIdx.z;
  const int K = side ? 512 : 1024;
  const int k = blockIdx.x;
  if (k >= K) return;
  const int zi = blockIdx.y;
  const float* Wp = side ? W1 : W2;
  int sel;
  if (side == 0) sel = (zi == 0) ? 0 : (zi == 1) ? 4 : (zi == 2) ? 5 : 3;
  else           sel = (zi == 0) ? 1 : (zi == 1) ? 2 : (zi == 2) ? 6 : 7;
  const float* Wg = (sel < 4) ? (gWs + (size_t)sel * 32768) : (gWd + (size_t)(sel - 4) * 32768);
  const int n = threadIdx.x;
  const float* wrow = Wp + (size_t)k * 256;
  float s0 = 0.f, s1 = 0.f, s2 = 0.f, s3 = 0.f;
  for (int m = 0; m < 256; m += 4) {
    s0 += wrow[m]     * Wg[m * 128 + n];
    s1 += wrow[m + 1] * Wg[(m + 1) * 128 + n];
    s2 += wrow[m + 2] * Wg[(m + 2) * 128 + n];
    s3 += wrow[m + 3] * Wg[(m + 3) * 128 + n];
  }
  us* out = side ? WcGE : WcPE;
  out[((size_t)zi * 128 + n) * K + k] = f2bf((s0 + s1) + (s2 + s3));
}

// combined bias: bc[side][zi][n] = sum_m bp[m]*Wg[m][n] + bg[n]
__global__ __launch_bounds__(128) void bcomb_k(
    const float* __restrict__ b2, const float* __restrict__ b1,
    const float* __restrict__ gWs, const float* __restrict__ gWd,
    const float* __restrict__ gbs, const float* __restrict__ gbd,
    float* __restrict__ bcPE, float* __restrict__ bcGE)
{
  int t = blockIdx.x * 128 + threadIdx.x;   // 1024 total
  int side = t >> 9, zi = (t >> 7) & 3, n = t & 127;
  int sel;
  if (side == 0) sel = (zi == 0) ? 0 : (zi == 1) ? 4 : (zi == 2) ? 5 : 3;
  else           sel = (zi == 0) ? 1 : (zi == 1) ? 2 : (zi == 2) ? 6 : 7;
  const float* Wg = (sel < 4) ? (gWs + (size_t)sel * 32768) : (gWd + (size_t)(sel - 4) * 32768);
  const float* bg = (sel < 4) ? (gbs + sel * 128) : (gbd + (sel - 4) * 128);
  const float* bp = side ? b1 : b2;
  float s = bg[n];
  for (int m = 0; m < 256; m++) s += bp[m] * Wg[m * 128 + n];
  (side ? bcGE : bcPE)[zi * 128 + n] = s;
}

// ------- fused feature GEMM: all 8 GAT feature matrices directly from PE/GE -------
// grid (idiv(M,64),1,2): side 0 = PE (K=1024) -> fs_all slots {0,1,3,6}; side 1 = GE (K=512) -> {2,4,5,7}.
// Block 512 thr = 8 waves; tile 64 rows x 512 cols; wave w covers combined cols w*64..+63 (zi=w>>1).
__global__ __launch_bounds__(512) void feat8_k(
    const float* __restrict__ PE, const float* __restrict__ GE,
    const us* __restrict__ WcPE, const us* __restrict__ WcGE,
    const float* __restrict__ bcPE, const float* __restrict__ bcGE,
    us* __restrict__ fs_all, int M)
{
  const int side = blockIdx.z;
  const float* A = side ? GE : PE;
  const us* Bt = side ? WcGE : WcPE;
  const float* bias = side ? bcGE : bcPE;
  const int K = side ? 512 : 1024;

  __shared__ us As[64 * 40];
  __shared__ us Bs[512 * 40];
  const int t = threadIdx.x;
  const int rowBase = blockIdx.x * 64;
  const int srow = t >> 3, skf = (t & 7) * 4;   // 8 thr/row, 4 floats each
  const int w = t >> 6, lane = t & 63;
  const int m16 = lane & 15, q = lane >> 4;

  f32x4 acc[4][4];
  const f32x4 zero = {0.f, 0.f, 0.f, 0.f};
#pragma unroll
  for (int i = 0; i < 4; i++)
#pragma unroll
    for (int j = 0; j < 4; j++) acc[i][j] = zero;

  int arow = rowBase + srow;
  if (arow >= M) arow = M - 1;
  const float* aptr = A + (size_t)arow * K;
  const us* bptr = Bt + (size_t)t * K;

  for (int k0 = 0; k0 < K; k0 += 32) {
    float4 x0 = *(const float4*)(aptr + k0 + skf);
    uint2 p;
    p.x = (unsigned)f2bf(x0.x) | ((unsigned)f2bf(x0.y) << 16);
    p.y = (unsigned)f2bf(x0.z) | ((unsigned)f2bf(x0.w) << 16);
    uint4 b0 = ((const uint4*)(bptr + k0))[0];
    uint4 b1v = ((const uint4*)(bptr + k0))[1];
    uint4 b2v = ((const uint4*)(bptr + k0))[2];
    uint4 b3v = ((const uint4*)(bptr + k0))[3];
    *(uint2*)&As[srow * 40 + skf] = p;
    ((uint4*)&Bs[t * 40])[0] = b0;
    ((uint4*)&Bs[t * 40])[1] = b1v;
    ((uint4*)&Bs[t * 40])[2] = b2v;
    ((uint4*)&Bs[t * 40])[3] = b3v;
    __syncthreads();
    s16x8 af[4], bfr[4];
#pragma unroll
    for (int mi = 0; mi < 4; mi++)
      af[mi] = *(const s16x8*)&As[(mi * 16 + m16) * 40 + q * 8];
#pragma unroll
    for (int ni = 0; ni < 4; ni++)
      bfr[ni] = *(const s16x8*)&Bs[(w * 64 + ni * 16 + m16) * 40 + q * 8];
#pragma unroll
    for (int mi = 0; mi < 4; mi++)
#pragma unroll
      for (int ni = 0; ni < 4; ni++)
        acc[mi][ni] = __builtin_amdgcn_mfma_f32_16x16x32_bf16(af[mi], bfr[ni], acc[mi][ni], 0, 0, 0);
    __syncthreads();
  }

  const int zi = w >> 1;
  int zslot;
  if (side == 0) zslot = (zi == 0) ? 0 : (zi == 1) ? 1 : (zi == 2) ? 3 : 6;
  else           zslot = (zi == 0) ? 2 : (zi == 1) ? 4 : (zi == 2) ? 5 : 7;
  us* C = fs_all + (size_t)zslot * M * 128;
#pragma unroll
  for (int ni = 0; ni < 4; ni++) {
    int col = (w & 1) * 64 + ni * 16 + m16;   // within 128
    float bcol = bias[zi * 128 + col];
#pragma unroll
    for (int mi = 0; mi < 4; mi++) {
#pragma unroll
      for (int r = 0; r < 4; r++) {
        int row = rowBase + mi * 16 + q * 4 + r;
        if (row < M) C[(size_t)row * 128 + col] = f2bf(acc[mi][ni][r] + bcol);
      }
    }
  }
}

// ---------------- CSR build v2: coarse-bucket two-phase ----------------
__global__ __launch_bounds__(256) void bhist_k(
    const int* __restrict__ e_aa, const int* __restrict__ e_ta,
    const int* __restrict__ e_tt, const int* __restrict__ e_at,
    int* __restrict__ bhist)
{
  int g = blockIdx.z;
  const int* e = g == 0 ? e_aa : g == 1 ? e_ta : g == 2 ? e_tt : e_at;
  const int* dstp = e + E_EDGES;
  __shared__ int lh[256];
  int t = threadIdx.x;
  lh[t] = 0;
  __syncthreads();
  int base = blockIdx.x * 2048;
#pragma unroll
  for (int r = 0; r < 8; r++) {
    int i = base + r * 256 + t;
    if (i < E_EDGES) atomicAdd(&lh[dstp[i] >> 8], 1);
  }
  __syncthreads();
  if (t < NBUCK && lh[t]) atomicAdd(&bhist[g * NBUCK + t], lh[t]);
}

__global__ __launch_bounds__(1024) void bscan_k(const int* __restrict__ bhist,
                                                int* __restrict__ bbase, int* __restrict__ bcur) {
  __shared__ int tmp[1024];
  int t = threadIdx.x;
  int v = (t < 4 * NBUCK) ? bhist[t] : 0;
  tmp[t] = v;
  __syncthreads();
  int x = v;
  for (int d = 1; d < 1024; d <<= 1) {
    int y = (t >= d) ? tmp[t - d] : 0;
    __syncthreads();
    x += y;
    tmp[t] = x;
    __syncthreads();
  }
  if (t < 4 * NBUCK) {
    int e = x - v;
    bbase[t] = e;
    bcur[t] = e;
  }
  if (t == 4 * NBUCK - 1) bbase[4 * NBUCK] = x;
}

__global__ __launch_bounds__(256) void binscatter_k(
    const int* __restrict__ e_aa, const int* __restrict__ e_ta,
    const int* __restrict__ e_tt, const int* __restrict__ e_at,
    int* __restrict__ bcur, unsigned int* __restrict__ epack)
{
  int g = blockIdx.z;
  const int* e = g == 0 ? e_aa : g == 1 ? e_ta : g == 2 ? e_tt : e_at;
  const int* srcp = e;
  const int* dstp = e + E_EDGES;
  const int base = blockIdx.x * 4096;
  const int cnt = min(4096, E_EDGES - base);
  __shared__ int lh[256], sc[256], lcur[256], gb[256];
  __shared__ unsigned int spack[4096];
  __shared__ unsigned short sbuck[4096];
  const int t = threadIdx.x;
  lh[t] = 0;
  __syncthreads();
  int ds[16], ss[16];
#pragma unroll
  for (int r = 0; r < 16; r++) {
    int i = r * 256 + t;
    if (i < cnt) {
      ds[r] = dstp[base + i];
      ss[r] = srcp[base + i];
      atomicAdd(&lh[ds[r] >> 8], 1);
    } else ds[r] = -1;
  }
  __syncthreads();
  int v = lh[t];
  sc[t] = v;
  __syncthreads();
  int x = v;
  for (int d = 1; d < 256; d <<= 1) {
    int y = (t >= d) ? sc[t - d] : 0;
    __syncthreads();
    x += y;
    sc[t] = x;
    __syncthreads();
  }
  lcur[t] = x - v;
  if (t < NBUCK) gb[t] = atomicAdd(&bcur[g * NBUCK + t], v);
  __syncthreads();
#pragma unroll
  for (int r = 0; r < 16; r++) {
    if (ds[r] >= 0) {
      int b = ds[r] >> 8;
      int rank = atomicAdd(&lcur[b], 1);
      spack[rank] = ((unsigned int)ds[r] << 16) | (unsigned int)ss[r];
      sbuck[rank] = (unsigned short)b;
    }
  }
  __syncthreads();
  for (int j = t; j < cnt; j += 256) {
    int b = sbuck[j];
    epack[gb[b] + (j - (sc[b] - lh[b]))] = spack[j];
  }
}

__global__ __launch_bounds__(256) void bucketscatter2_k(
    const int* __restrict__ bbase, const unsigned int* __restrict__ epack,
    int* __restrict__ esrc_all, int* __restrict__ offs4)
{
  int g = blockIdx.z, b = blockIdx.x;
  int gb = g * NBUCK + b;
  int start = bbase[gb], end = bbase[gb + 1];
  int ndst = min(256, N_NODES - (b << 8));
  __shared__ int lh[256], cur[256];
  int t = threadIdx.x;
  lh[t] = 0;
  __syncthreads();
  for (int i = start + t; i < end; i += 256)
    atomicAdd(&lh[(epack[i] >> 16) & 255], 1);
  __syncthreads();
  int v = lh[t];
  cur[t] = v;
  __syncthreads();
  int x = v;
  for (int d = 1; d < 256; d <<= 1) {
    int y = (t >= d) ? cur[t - d] : 0;
    __syncthreads();
    x += y;
    cur[t] = x;
    __syncthreads();
  }
  int mybase = start + x - v;
  if (t < ndst) offs4[g * N_NODES + (b << 8) + t] = mybase;
  cur[t] = mybase;
  __syncthreads();
  if (gb == 4 * NBUCK - 1 && t == 0) offs4[NG4] = end;
  unsigned int pk = (start + t < end) ? epack[start + t] : 0u;
  for (int i = start + t; i < end; i += 256) {
    unsigned int nk = (i + 256 < end) ? epack[i + 256] : 0u;
    int dl = (pk >> 16) & 255;
    int pos = atomicAdd(&cur[dl], 1);
    esrc_all[pos] = (int)(pk & 0xffffu);
    pk = nk;
  }
}

// -------- GATv2 edge-softmax + aggregate, all 4 graphs (z=graph) --------
__global__ __launch_bounds__(256) void aggregate4_k(
    const us* __restrict__ fs_all, const float* __restrict__ gattn,
    const int* __restrict__ offs4, const int* __restrict__ esrc_all,
    us* __restrict__ zb_all, int n)
{
  int g = blockIdx.z;
  const us* fs = fs_all + (size_t)(2 * g) * n * 128;
  const us* fd = fs_all + (size_t)(2 * g + 1) * n * 128;
  const float* attn = gattn + g * 128;
  us* zout = zb_all + (size_t)g * n * 128;
  const int* offs = offs4 + (size_t)g * n;

  int node = blockIdx.x * 4 + (threadIdx.x >> 6);
  int lane = threadIdx.x & 63;
  int slot = lane >> 4;
  int sl = lane & 15;
  if (node >= n) return;

  uint4 fdu = *(const uint4*)(fd + (size_t)node * 128 + sl * 8);
  float fdv[8];
  fdv[0] = bflo(fdu.x); fdv[1] = bfhi(fdu.x);
  fdv[2] = bflo(fdu.y); fdv[3] = bfhi(fdu.y);
  fdv[4] = bflo(fdu.z); fdv[5] = bfhi(fdu.z);
  fdv[6] = bflo(fdu.w); fdv[7] = bfhi(fdu.w);
  float4 at0 = *(const float4*)(attn + sl * 8);
  float4 at1 = *(const float4*)(attn + sl * 8 + 4);
  float atv[8] = {at0.x, at0.y, at0.z, at0.w, at1.x, at1.y, at1.z, at1.w};

  int s0 = offs[node], s1 = offs[node + 1];
  float acc[8] = {0.f, 0.f, 0.f, 0.f, 0.f, 0.f, 0.f, 0.f};
  float sacc = 0.f;

  int i = s0 + slot;
  int src = (i < s1) ? esrc_all[i] : 0;
  while (i < s1) {
    int ni = i + 4;
    int nsrc = (ni < s1) ? esrc_all[ni] : 0;
    uint4 fu = *(const uint4*)(fs + (size_t)src * 128 + sl * 8);
    float fv[8];
    fv[0] = bflo(fu.x); fv[1] = bfhi(fu.x);
    fv[2] = bflo(fu.y); fv[3] = bfhi(fu.y);
    fv[4] = bflo(fu.z); fv[5] = bfhi(fu.z);
    fv[6] = bflo(fu.w); fv[7] = bfhi(fu.w);
    float p = 0.f;
#pragma unroll
    for (int j = 0; j < 8; j++) {
      float tt = fv[j] + fdv[j];
      tt = (tt > 0.f) ? tt : 0.2f * tt;
      p += tt * atv[j];
    }
    p += __shfl_xor(p, 1);
    p += __shfl_xor(p, 2);
    float ex = __expf(p);
    sacc += ex;
#pragma unroll
    for (int j = 0; j < 8; j++) acc[j] += ex * fv[j];
    i = ni;
    src = nsrc;
  }

#pragma unroll
  for (int j = 0; j < 8; j++) {
    acc[j] += __shfl_xor(acc[j], 16);
    acc[j] += __shfl_xor(acc[j], 32);
  }
  sacc += __shfl_xor(sacc, 16);
  sacc += __shfl_xor(sacc, 32);

  if (slot == 0) {
    float inv = (s1 > s0) ? (1.f / sacc) : 0.f;
    uint4 o;
    o.x = (unsigned)f2bf(fmaxf(acc[0] * inv, 0.f)) | ((unsigned)f2bf(fmaxf(acc[1] * inv, 0.f)) << 16);
    o.y = (unsigned)f2bf(fmaxf(acc[2] * inv, 0.f)) | ((unsigned)f2bf(fmaxf(acc[3] * inv, 0.f)) << 16);
    o.z = (unsigned)f2bf(fmaxf(acc[4] * inv, 0.f)) | ((unsigned)f2bf(fmaxf(acc[5] * inv, 0.f)) << 16);
    o.w = (unsigned)f2bf(fmaxf(acc[6] * inv, 0.f)) | ((unsigned)f2bf(fmaxf(acc[7] * inv, 0.f)) << 16);
    *(uint4*)(zout + (size_t)node * 128 + sl * 8) = o;
  }
}

// ---------------- semantic attention, MFMA-fused ----------------
__global__ __launch_bounds__(256) void satt_mfma_k(
    const us* __restrict__ z0, const us* __restrict__ z1,
    const us* __restrict__ Wat, const float* __restrict__ ba,
    const float* __restrict__ Wo, float* __restrict__ w_acc, int M)
{
  __shared__ us As[128 * 40];
  __shared__ us Bs[128 * 40];
  const us* Z = blockIdx.z ? z1 : z0;
  const int t = threadIdx.x;
  const int rowBase = blockIdx.y * 128;
  const int srow = t >> 1, sk = (t & 1) * 16;
  const int w = t >> 6, lane = t & 63;
  const int wm = w >> 1, wn = w & 1;
  const int m16 = lane & 15, q = lane >> 4;

  f32x4 acc[4][4];
  const f32x4 zero = {0.f, 0.f, 0.f, 0.f};
#pragma unroll
  for (int i = 0; i < 4; i++)
#pragma unroll
    for (int j = 0; j < 4; j++) acc[i][j] = zero;

  int arow = rowBase + srow;
  if (arow >= M) arow = M - 1;
  const us* aptr = Z + (size_t)arow * 128;
  const us* bptr = Wat + (size_t)srow * 128;

  for (int k0 = 0; k0 < 128; k0 += 32) {
    uint4 a0 = ((const uint4*)(aptr + k0 + sk))[0];
    uint4 a1 = ((const uint4*)(aptr + k0 + sk))[1];
    uint4 b0 = ((const uint4*)(bptr + k0 + sk))[0];
    uint4 b1 = ((const uint4*)(bptr + k0 + sk))[1];
    ((uint4*)&As[srow * 40 + sk])[0] = a0;
    ((uint4*)&As[srow * 40 + sk])[1] = a1;
    ((uint4*)&Bs[srow * 40 + sk])[0] = b0;
    ((uint4*)&Bs[srow * 40 + sk])[1] = b1;
    __syncthreads();
    s16x8 af[4], bfr[4];
#pragma unroll
    for (int mi = 0; mi < 4; mi++)
      af[mi] = *(const s16x8*)&As[(wm * 64 + mi * 16 + m16) * 40 + q * 8];
#pragma unroll
    for (int ni = 0; ni < 4; ni++)
      bfr[ni] = *(const s16x8*)&Bs[(wn * 64 + ni * 16 + m16) * 40 + q * 8];
#pragma unroll
    for (int mi = 0; mi < 4; mi++)
#pragma unroll
      for (int ni = 0; ni < 4; ni++)
        acc[mi][ni] = __builtin_amdgcn_mfma_f32_16x16x32_bf16(af[mi], bfr[ni], acc[mi][ni], 0, 0, 0);
    __syncthreads();
  }

  float s = 0.f;
#pragma unroll
  for (int ni = 0; ni < 4; ni++) {
    int col = wn * 64 + ni * 16 + m16;
    float bcol = ba[col], wcol = Wo[col];
#pragma unroll
    for (int mi = 0; mi < 4; mi++) {
#pragma unroll
      for (int r = 0; r < 4; r++) {
        int row = rowBase + wm * 64 + mi * 16 + q * 4 + r;
        if (row < M) s += tanhf(acc[mi][ni][r] + bcol) * wcol;
      }
    }
  }
  for (int d = 1; d < 64; d <<= 1) s += __shfl_xor(s, d);
  __shared__ float red[4];
  if (lane == 0) red[w] = s;
  __syncthreads();
  if (t == 0) atomicAdd(&w_acc[blockIdx.z], red[0] + red[1] + red[2] + red[3]);
}

__global__ void beta_k(const float* __restrict__ w_acc, float* __restrict__ beta, float invn) {
  if (threadIdx.x == 0 && blockIdx.x == 0) {
    float w0 = w_acc[0] * invn, w1 = w_acc[1] * invn;
    float m = fmaxf(w0, w1);
    float e0 = expf(w0 - m), e1 = expf(w1 - m);
    float s = e0 + e1;
    beta[0] = e0 / s; beta[1] = e1 / s;
    float w2 = w_acc[2] * invn, w3 = w_acc[3] * invn;
    float m2 = fmaxf(w2, w3);
    float e2 = expf(w2 - m2), e3 = expf(w3 - m2);
    float s2 = e2 + e3;
    beta[2] = e2 / s2; beta[3] = e3 / s2;
  }
}

static __device__ __forceinline__ unsigned int comb2(unsigned int a, unsigned int b, float b0, float b1) {
  float lo = bflo(a) * b0 + bflo(b) * b1;
  float hi = bfhi(a) * b0 + bfhi(b) * b1;
  return (unsigned int)f2bf(lo) | ((unsigned int)f2bf(hi) << 16);
}

__global__ __launch_bounds__(256) void combine2_k(const us* __restrict__ zb_all,
                                                  const float* __restrict__ beta,
                                                  us* __restrict__ haob, us* __restrict__ htob, int n8) {
  int z = blockIdx.z;
  const us* za = zb_all + (size_t)(2 * z) * N_NODES * 128;
  const us* zbv = zb_all + (size_t)(2 * z + 1) * N_NODES * 128;
  float b0 = beta[2 * z], b1 = beta[2 * z + 1];
  us* outv = z ? htob : haob;
  for (int i = blockIdx.x * 256 + threadIdx.x; i < n8; i += gridDim.x * 256) {
    uint4 a = ((const uint4*)za)[i];
    uint4 b = ((const uint4*)zbv)[i];
    uint4 o;
    o.x = comb2(a.x, b.x, b0, b1);
    o.y = comb2(a.y, b.y, b0, b1);
    o.z = comb2(a.z, b.z, b0, b1);
    o.w = comb2(a.w, b.w, b0, b1);
    ((uint4*)outv)[i] = o;
  }
}

// -------- predictor fully fused --------
__global__ __launch_bounds__(256) void pred_fused_k(
    const us* __restrict__ haob, const us* __restrict__ htob,
    const int* __restrict__ pos_e, const int* __restrict__ neg_e,
    const us* __restrict__ prW1t, const float* __restrict__ prb1,
    const float* __restrict__ prW2, const float* __restrict__ prb2,
    float* __restrict__ out, int M)
{
  __shared__ us As[128 * 40];
  __shared__ us Bs[128 * 40];
  const int z = blockIdx.z;
  const int* pe = z ? neg_e : pos_e;
  float* o = out + (size_t)z * M;

  const int t = threadIdx.x;
  const int rowBase = blockIdx.x * 128;
  const int srow = t >> 1, sk = (t & 1) * 16;
  const int w = t >> 6, lane = t & 63;
  const int wm = w >> 1, wn = w & 1;
  const int m16 = lane & 15, q = lane >> 4;

  f32x4 acc[4][4];
  const f32x4 zero = {0.f, 0.f, 0.f, 0.f};
#pragma unroll
  for (int i = 0; i < 4; i++)
#pragma unroll
    for (int j = 0; j < 4; j++) acc[i][j] = zero;

  int arow = rowBase + srow;
  if (arow >= M) arow = M - 1;
  const int srcn = pe[arow];
  const int dstn = pe[M + arow];
  const us* bptr = prW1t + (size_t)srow * 256;

  for (int k0 = 0; k0 < 256; k0 += 32) {
    const us* asrc = (k0 < 128) ? (haob + (size_t)srcn * 128 + k0 + sk)
                                : (htob + (size_t)dstn * 128 + (k0 - 128) + sk);
    uint4 a0 = ((const uint4*)asrc)[0];
    uint4 a1 = ((const uint4*)asrc)[1];
    uint4 b0 = ((const uint4*)(bptr + k0 + sk))[0];
    uint4 b1 = ((const uint4*)(bptr + k0 + sk))[1];
    ((uint4*)&As[srow * 40 + sk])[0] = a0;
    ((uint4*)&As[srow * 40 + sk])[1] = a1;
    ((uint4*)&Bs[srow * 40 + sk])[0] = b0;
    ((uint4*)&Bs[srow * 40 + sk])[1] = b1;
    __syncthreads();
    s16x8 af[4], bfr[4];
#pragma unroll
    for (int mi = 0; mi < 4; mi++)
      af[mi] = *(const s16x8*)&As[(wm * 64 + mi * 16 + m16) * 40 + q * 8];
#pragma unroll
    for (int ni = 0; ni < 4; ni++)
      bfr[ni] = *(const s16x8*)&Bs[(wn * 64 + ni * 16 + m16) * 40 + q * 8];
#pragma unroll
    for (int mi = 0; mi < 4; mi++)
#pragma unroll
      for (int ni = 0; ni < 4; ni++)
        acc[mi][ni] = __builtin_amdgcn_mfma_f32_16x16x32_bf16(af[mi], bfr[ni], acc[mi][ni], 0, 0, 0);
    __syncthreads();
  }

  float* rsum = (float*)As;
  if (t < 128) rsum[t] = 0.f;
  __syncthreads();
  float bcol[4], w2c[4];
#pragma unroll
  for (int ni = 0; ni < 4; ni++) {
    int col = wn * 64 + ni * 16 + m16;
    bcol[ni] = prb1[col];
    w2c[ni] = prW2[col];
  }
#pragma unroll
  for (int mi = 0; mi < 4; mi++) {
#pragma unroll
    for (int r = 0; r < 4; r++) {
      float s = 0.f;
#pragma unroll
      for (int ni = 0; ni < 4; ni++)
        s += fmaxf(acc[mi][ni][r] + bcol[ni], 0.f) * w2c[ni];
      s += __shfl_xor(s, 1);
      s += __shfl_xor(s, 2);
      s += __shfl_xor(s, 4);
      s += __shfl_xor(s, 8);
      if (m16 == 0) atomicAdd(&rsum[wm * 64 + mi * 16 + q * 4 + r], s);
    }
  }
  __syncthreads();
  if (t < 128) {
    int row = rowBase + t;
    if (row < M) o[row] = 1.f / (1.f + expf(-(rsum[t] + prb2[0])));
  }
}

extern "C" void kernel_launch(void* const* d_in, const int* in_sizes, int n_in,
                              void* d_out, int out_size, void* d_ws, size_t ws_size,
                              hipStream_t stream) {
  const float* PE   = (const float*)d_in[0];
  const float* GE   = (const float*)d_in[1];
  const float* W1   = (const float*)d_in[2];
  const float* b1   = (const float*)d_in[3];
  const float* W2   = (const float*)d_in[4];
  const float* b2   = (const float*)d_in[5];
  const float* gWs  = (const float*)d_in[6];
  const float* gbs  = (const float*)d_in[7];
  const float* gWd  = (const float*)d_in[8];
  const float* gbd  = (const float*)d_in[9];
  const float* gattn= (const float*)d_in[10];
  const float* pW1  = (const float*)d_in[11];
  const float* pb1  = (const float*)d_in[12];
  const float* pW2  = (const float*)d_in[13];
  const float* gaW1 = (const float*)d_in[14];
  const float* gab1 = (const float*)d_in[15];
  const float* gaW2 = (const float*)d_in[16];
  const float* prW1 = (const float*)d_in[17];
  const float* prb1 = (const float*)d_in[18];
  const float* prW2 = (const float*)d_in[19];
  const float* prb2 = (const float*)d_in[20];
  const int* e_aa = (const int*)d_in[21];
  const int* e_ta = (const int*)d_in[22];
  const int* e_tt = (const int*)d_in[23];
  const int* e_at = (const int*)d_in[24];
  const int* pos_e = (const int*)d_in[25];
  const int* neg_e = (const int*)d_in[26];
  float* out = (float*)d_out;

  // ---- workspace layout ----
  us* usws = (us*)d_ws;
  size_t o = 0;
  us* fs_all = usws + o; o += (size_t)8 * N_NODES * 128;   // 51.2M us
  us* zb_all = usws + o; o += (size_t)4 * N_NODES * 128;   // 25.6M us
  us* haob   = usws + o; o += (size_t)N_NODES * 128;
  us* htob   = usws + o; o += (size_t)N_NODES * 128;
  us* WcPE   = usws + o; o += 524288;   // [4][128][1024] bf16
  us* WcGE   = usws + o; o += 262144;   // [4][128][512]
  us* prW1t  = usws + o; o += 32768;
  us* WaPt   = usws + o; o += 16384;
  us* WaGt   = usws + o; o += 16384;
  float* bcPE = (float*)(usws + o); o += 1024;   // 512 f32
  float* bcGE = (float*)(usws + o); o += 1024;
  float* w_acc = (float*)(usws + o); o += 16;
  float* beta  = w_acc + 4;
  int* ib = (int*)(usws + o);
  size_t io = 0;
  int* bhist = ib + io; io += 1024;
  int* bbase = ib + io; io += 1024;
  int* bcur  = ib + io; io += 1024;
  int* offs4 = ib + io; io += NG4 + 4;
  int* esrc  = ib + io; io += ETOT;
  unsigned int* epack = (unsigned int*)zb_all;   // dead until aggregate4_k

  dim3 blk128(128), blk256(256), blk512(512), blk1024(1024);
  const int MT = idiv(N_NODES, 128);   // 391
  const int MT64 = idiv(N_NODES, 64);  // 782
  const int ET = idiv(EP_EDGES, 128);  // 1563

  // 1) small weight preps (combined GEMM weights + transposes + biases)
  wcomb_k<<<dim3(1024, 4, 2), blk128, 0, stream>>>(W2, W1, gWs, gWd, WcPE, WcGE);
  bcomb_k<<<dim3(8), blk128, 0, stream>>>(b2, b1, gWs, gWd, gbs, gbd, bcPE, bcGE);
  wtrans3_k<<<dim3(32, 1, 3), blk256, 0, stream>>>(prW1, pW1, gaW1, prW1t, WaPt, WaGt);

  // 2) fused feature GEMM: all 8 GAT feature matrices directly from PE/GE
  feat8_k<<<dim3(MT64, 1, 2), blk512, 0, stream>>>(PE, GE, WcPE, WcGE, bcPE, bcGE, fs_all, N_NODES);

  // 3-6) CSR build v2 (bucketed two-phase, dense writes)
  hipMemsetAsync(bhist, 0, 4 * NBUCK * sizeof(int), stream);
  bhist_k<<<dim3(idiv(E_EDGES, 2048), 1, 4), blk256, 0, stream>>>(e_aa, e_ta, e_tt, e_at, bhist);
  bscan_k<<<1, blk1024, 0, stream>>>(bhist, bbase, bcur);
  binscatter_k<<<dim3(idiv(E_EDGES, 4096), 1, 4), blk256, 0, stream>>>(e_aa, e_ta, e_tt, e_at, bcur, epack);
  bucketscatter2_k<<<dim3(NBUCK, 1, 4), blk256, 0, stream>>>(bbase, epack, esrc, offs4);

  // 7) all 4 edge-softmax aggregations
  aggregate4_k<<<dim3(idiv(N_NODES, 4), 1, 4), blk256, 0, stream>>>(fs_all, gattn, offs4, esrc, zb_all, N_NODES);

  // 8-9) semantic attention
  hipMemsetAsync(w_acc, 0, 4 * sizeof(float), stream);
  satt_mfma_k<<<dim3(1, MT, 2), blk256, 0, stream>>>(
      zb_all, zb_all + (size_t)N_NODES * 128, WaPt, pb1, pW2, w_acc + 0, N_NODES);
  satt_mfma_k<<<dim3(1, MT, 2), blk256, 0, stream>>>(
      zb_all + (size_t)2 * N_NODES * 128, zb_all + (size_t)3 * N_NODES * 128, WaGt, gab1, gaW2, w_acc + 2, N_NODES);
  beta_k<<<1, 64, 0, stream>>>(w_acc, beta, 1.0f / (float)N_NODES);

  // 10) combine both groups
  combine2_k<<<dim3(2048, 1, 2), blk256, 0, stream>>>(zb_all, beta, haob, htob, N_NODES * 128 / 8);

  // 11) fully fused predictor (pos+neg)
  pred_fused_k<<<dim3(ET, 1, 2), blk256, 0, stream>>>(
      haob, htob, pos_e, neg_e, prW1t, prb1, prW2, prb2, out, EP_EDGES);
}